// Round 9
// baseline (49.641 us; speedup 1.0000x reference)
//
#include <hip/hip_runtime.h>
#include <hip/hip_bf16.h>

#define NTOK 16384
#define DIM  2048
#define NE   64
#define TPB  64                 // tokens per block
#define NCH  32                 // k-chunks of 64
#define RING 4
#define SLOTB 32768             // 16 KB X + 16 KB B per slot
#define NKS_ALL (DIM / 32)      // 64 total k-steps

typedef __attribute__((ext_vector_type(8))) short  short8;
typedef __attribute__((ext_vector_type(4))) float  f32x4;

static __device__ __forceinline__ unsigned short f2bf(float f) {
    unsigned u = __float_as_uint(f);
    unsigned r = (u + 0x7fffu + ((u >> 16) & 1u)) >> 16;   // RNE
    return (unsigned short)r;
}
static __device__ __forceinline__ float bf2f(unsigned short h) {
    return __uint_as_float(((unsigned)h) << 16);
}
static __device__ __forceinline__ void cvt_pair(float x0, float x1,
                                                unsigned& hi, unsigned& lo) {
    union { __hip_bfloat162 b; unsigned u; } h, l;
    h.b = __float22bfloat162_rn(float2{x0, x1});           // v_cvt_pk_bf16_f32
    float h0 = __uint_as_float(h.u << 16);
    float h1 = __uint_as_float(h.u & 0xffff0000u);
    l.b = __float22bfloat162_rn(float2{x0 - h0, x1 - h1});
    hi = h.u; lo = l.u;
}

#define GLOAD_LDS(gp, lp) \
    __builtin_amdgcn_global_load_lds( \
        (const __attribute__((address_space(1))) unsigned int*)(const void*)(gp), \
        (__attribute__((address_space(3))) unsigned int*)(void*)(lp), 16, 0, 0)

// ---- prologue: split W into hi/lo bf16, packed in MFMA B-fragment order ----
__global__ void pack_w(const float* __restrict__ W,
                       unsigned short* __restrict__ WH,
                       unsigned short* __restrict__ WL) {
    int idx = blockIdx.x * 256 + threadIdx.x;
    if (idx >= DIM * NE) return;
    int k = idx / NE, e = idx % NE;
    float w = W[idx];
    unsigned short h = f2bf(w);
    unsigned short l = f2bf(w - bf2f(h));
    int etile = e >> 4, col = e & 15;
    int kstep = k >> 5, lsub = (k >> 3) & 3, j = k & 7;
    size_t off = (((size_t)etile * NKS_ALL + kstep) * 64 + (lsub * 16 + col)) * 8 + j;
    WH[off] = h;
    WL[off] = l;
}

// ---- main: async-staged (global_load_lds + counted vmcnt) 3-pass MFMA ----
__global__ __launch_bounds__(512, 1) void router_mfma(
    const float* __restrict__ X,
    const unsigned short* __restrict__ WH,
    const unsigned short* __restrict__ WL,
    const float* __restrict__ B, float* __restrict__ out)
{
    __shared__ __align__(16) unsigned char ring[RING * SLOTB];   // 128 KB
    __shared__ float lg[TPB][65];                                // 16.6 KB

    const int tid  = threadIdx.x;
    const int lane = tid & 63;
    const int wv   = tid >> 6;                                  // 0..7
    const int tt   = __builtin_amdgcn_readfirstlane(wv & 3);    // token tile 0..3
    const int eh   = __builtin_amdgcn_readfirstlane(wv >> 2);   // expert half 0..1
    const int t0   = blockIdx.x * TPB;

    // ---- staging helper (2 X instrs + 2 B instrs per wave per chunk) ----
#define STAGE_CHUNK(c) do {                                                      \
    unsigned char* slot_ = ring + ((c) & 3) * SLOTB;                             \
    _Pragma("unroll")                                                            \
    for (int i_ = 0; i_ < 2; ++i_) {                                             \
        int row_ = wv * 8 + i_ * 4 + (lane >> 4);                                \
        int p_   = lane & 15;                                                    \
        int b_   = (p_ & 8) | ((p_ & 7) ^ (row_ & 7));                           \
        const float* g_ = X + (size_t)(t0 + row_) * DIM + (c) * 64 + b_ * 4;     \
        GLOAD_LDS(g_, slot_ + (wv * 2 + i_) * 1024);                             \
    }                                                                            \
    _Pragma("unroll")                                                            \
    for (int i_ = 0; i_ < 2; ++i_) {                                             \
        int idx_ = wv * 2 + i_;               /* = ksl*8 + etg*2 + hl */         \
        int ksl_ = idx_ >> 3, etg_ = (idx_ >> 1) & 3, hl_ = idx_ & 1;            \
        int ks_  = (c) * 2 + ksl_;                                               \
        const unsigned short* s_ = (hl_ ? WL : WH) +                             \
            (((size_t)etg_ * NKS_ALL + ks_) * 64 + lane) * 8;                    \
        GLOAD_LDS(s_, slot_ + 16384 + idx_ * 1024);                              \
    }                                                                            \
  } while (0)

    f32x4 acc[2];
    acc[0] = (f32x4){0.f, 0.f, 0.f, 0.f};
    acc[1] = (f32x4){0.f, 0.f, 0.f, 0.f};

    // prologue: 3 chunks in flight
    STAGE_CHUNK(0);
    STAGE_CHUNK(1);
    STAGE_CHUNK(2);

    const int g   = lane >> 4;      // k-quarter 0..3
    const int r   = lane & 15;      // A row within tile
    const int row = tt * 16 + r;

#pragma unroll 1
    for (int c = 0; c < NCH; ++c) {
        // T4: counted wait — never drain to 0 in steady state
        if (c < NCH - 2)       asm volatile("s_waitcnt vmcnt(8)" ::: "memory");
        else if (c == NCH - 2) asm volatile("s_waitcnt vmcnt(4)" ::: "memory");
        else                   asm volatile("s_waitcnt vmcnt(0)" ::: "memory");
        __builtin_amdgcn_s_barrier();
        __builtin_amdgcn_sched_barrier(0);

        if (c + 3 < NCH) STAGE_CHUNK(c + 3);
        __builtin_amdgcn_sched_barrier(0);

        unsigned char* slot = ring + (c & 3) * SLOTB;
        const unsigned char* bbase = slot + 16384;

        // B-frags: lane-linear ds_read_b128, conflict-free
        short8 bh[2][2], bl[2][2];   // [ksl][et]
#pragma unroll
        for (int ksl = 0; ksl < 2; ++ksl)
#pragma unroll
            for (int et = 0; et < 2; ++et) {
                int etg = eh * 2 + et;
                bh[ksl][et] = *(const short8*)(bbase + (ksl * 8 + etg * 2 + 0) * 1024 + lane * 16);
                bl[ksl][et] = *(const short8*)(bbase + (ksl * 8 + etg * 2 + 1) * 1024 + lane * 16);
            }

#pragma unroll
        for (int cs = 0; cs < 2; ++cs) {
            // A-frag: 8 consecutive fp32 via 2 swizzled ds_read_b128
            int b0 = cs * 8 + 2 * g;
            int p0 = (b0 & 8) | ((b0 & 7) ^ (r & 7));
            int p1 = ((b0 + 1) & 8) | (((b0 + 1) & 7) ^ (r & 7));
            float4 xa = *(const float4*)(slot + row * 256 + p0 * 16);
            float4 xb = *(const float4*)(slot + row * 256 + p1 * 16);

            union { unsigned u[4]; short8 s8; } ah, al;
            cvt_pair(xa.x, xa.y, ah.u[0], al.u[0]);
            cvt_pair(xa.z, xa.w, ah.u[1], al.u[1]);
            cvt_pair(xb.x, xb.y, ah.u[2], al.u[2]);
            cvt_pair(xb.z, xb.w, ah.u[3], al.u[3]);

#pragma unroll
            for (int et = 0; et < 2; ++et) {
                acc[et] = __builtin_amdgcn_mfma_f32_16x16x32_bf16(ah.s8, bh[cs][et], acc[et], 0, 0, 0);
                acc[et] = __builtin_amdgcn_mfma_f32_16x16x32_bf16(ah.s8, bl[cs][et], acc[et], 0, 0, 0);
                acc[et] = __builtin_amdgcn_mfma_f32_16x16x32_bf16(al.s8, bh[cs][et], acc[et], 0, 0, 0);
            }
        }
    }

    // ---- epilogue: bias + lg, store logits, top-2 ----
#pragma unroll
    for (int et = 0; et < 2; ++et) {
        int etg = eh * 2 + et;
        float bias = B[etg * 16 + r];          // C-frag col = lane&15 = r
#pragma unroll
        for (int q = 0; q < 4; ++q)
            lg[tt * 16 + g * 4 + q][etg * 16 + r] = acc[et][q] + bias;
    }
    __syncthreads();

    float* out_nv  = out + (size_t)NTOK * NE;
    float* out_idx = out_nv + (size_t)NTOK * 2;

#pragma unroll
    for (int k = 0; k < 2; ++k) {
        const int idx = tid + k * 512;          // 1024 quads = 64 tok x 16
        const int rt = idx >> 4;
        const int re = (idx & 15) * 4;
        float4 s;
        s.x = lg[rt][re + 0];
        s.y = lg[rt][re + 1];
        s.z = lg[rt][re + 2];
        s.w = lg[rt][re + 3];
        *(float4*)&out[(size_t)(t0 + rt) * NE + re] = s;
    }

    if (tid < 4 * TPB) {
        const int tk = tid >> 2;         // token 0..63
        const int q  = tid & 3;          // expert quarter
        float m1 = -1e30f, m2 = -1e30f;
        int   i1 = 0, i2 = 0;
#pragma unroll
        for (int j = 0; j < 16; ++j) {
            int   e = q * 16 + j;
            float v = lg[tk][e];
            if (v > m1)      { m2 = m1; i2 = i1; m1 = v; i1 = e; }
            else if (v > m2) { m2 = v;  i2 = e; }
        }
#pragma unroll
        for (int d = 1; d <= 2; d <<= 1) {
            float om1 = __shfl_xor(m1, d);
            int   oi1 = __shfl_xor(i1, d);
            float om2 = __shfl_xor(m2, d);
            int   oi2 = __shfl_xor(i2, d);
            bool agt = (m1 > om1) || (m1 == om1 && i1 < oi1);
            float a1 = agt ? m1 : om1;  int ai1 = agt ? i1 : oi1;
            float c2 = agt ? m2 : om2;  int ci2 = agt ? i2 : oi2;
            float c1 = agt ? om1 : m1;  int ci1 = agt ? oi1 : i1;
            bool sgt = (c2 > c1) || (c2 == c1 && ci2 < ci1);
            m1 = a1; i1 = ai1;
            m2 = sgt ? c2 : c1; i2 = sgt ? ci2 : ci1;
        }
        if (q == 0) {
            float e2  = expf(m2 - m1);
            float inv = 1.f / (1.f + e2);
            int t = t0 + tk;
            out_nv[t * 2 + 0]  = inv;
            out_nv[t * 2 + 1]  = e2 * inv;
            out_idx[t * 2 + 0] = (float)i1;
            out_idx[t * 2 + 1] = (float)i2;
        }
    }
}

extern "C" void kernel_launch(void* const* d_in, const int* in_sizes, int n_in,
                              void* d_out, int out_size, void* d_ws, size_t ws_size,
                              hipStream_t stream) {
    const float* X = (const float*)d_in[0];
    const float* W = (const float*)d_in[1];
    const float* B = (const float*)d_in[2];
    float* out = (float*)d_out;

    unsigned short* WH = (unsigned short*)d_ws;          // 256 KB
    unsigned short* WL = WH + (size_t)DIM * NE;          // +256 KB

    hipLaunchKernelGGL(pack_w, dim3((DIM * NE + 255) / 256), dim3(256), 0, stream, W, WH, WL);
    hipLaunchKernelGGL(router_mfma, dim3(NTOK / TPB), dim3(512), 0, stream, X, WH, WL, B, out);
}